// Round 12
// baseline (379.125 us; speedup 1.0000x reference)
//
#include <hip/hip_runtime.h>

#define EPSV 1e-5f

typedef __bf16 bf16x8 __attribute__((ext_vector_type(8)));
typedef float f32x4 __attribute__((ext_vector_type(4)));
typedef unsigned int u32x4 __attribute__((ext_vector_type(4)));
typedef unsigned short u16x4 __attribute__((ext_vector_type(4)));

__device__ __forceinline__ unsigned short f2bf(float f) {
  return __builtin_bit_cast(unsigned short, static_cast<__bf16>(f));
}

constexpr int Himg = 112, Wimg = 112, HWp = Himg * Wimg;  // 12544

// ---------------------------------------------------------------------------
// prep_misc: pack weights into per-lane MFMA A-fragment order + BN scale/shift.
//   wPack[i], i = ((tap*2+ks)*4 + c)*512 + l*8 + j  (bf16)
//   co = c*16+(l&15), ci = ks*32+(l>>4)*8+j
// ---------------------------------------------------------------------------
__global__ __launch_bounds__(256) void prep_misc(
    const float* __restrict__ w1, const float* __restrict__ w2,
    const float* __restrict__ g1, const float* __restrict__ b1,
    const float* __restrict__ m1, const float* __restrict__ v1,
    const float* __restrict__ g2, const float* __restrict__ b2,
    const float* __restrict__ m2, const float* __restrict__ v2,
    unsigned short* __restrict__ wt1, unsigned short* __restrict__ wt2,
    float* __restrict__ prm)
{
  int id = blockIdx.x * 256 + threadIdx.x;
  for (int i = id; i < 9 * 2 * 4 * 512; i += gridDim.x * 256) {
    int j   = i & 7;
    int l   = (i >> 3) & 63;
    int c   = (i >> 9) & 3;
    int ks  = (i >> 11) & 1;
    int tap = i >> 12;
    int co  = c * 16 + (l & 15);
    int ci  = ks * 32 + (l >> 4) * 8 + j;
    int kh  = tap / 3, kw = tap - kh * 3;
    int src = ((co * 64 + ci) * 3 + kh) * 3 + kw;
    wt1[i] = f2bf(w1[src]);
    wt2[i] = f2bf(w2[src]);
  }
  if (id < 64) {
    float s1 = g1[id] * rsqrtf(v1[id] + EPSV);
    prm[id]      = s1;
    prm[64 + id] = b1[id] - m1[id] * s1;
    float s2 = g2[id] * rsqrtf(v2[id] + EPSV);
    prm[128 + id] = s2;
    prm[192 + id] = b2[id] - m2[id] * s2;
  }
}

// ---------------------------------------------------------------------------
// prep_x0: x NCHW f32 -> x0 = BN0(x) as NHWC bf16
// ---------------------------------------------------------------------------
__global__ __launch_bounds__(256) void prep_x0(
    const float* __restrict__ x,
    const float* __restrict__ g0, const float* __restrict__ b0,
    const float* __restrict__ m0, const float* __restrict__ v0,
    unsigned short* __restrict__ x0)
{
  __shared__ float sc[64];
  __shared__ float sh[64];
  __shared__ float tile[64][113];
  const int t = threadIdx.x;
  const int bid = blockIdx.x;          // n*112 + h
  const int n = bid / 112, h = bid - n * 112;
  if (t < 64) {
    float s = g0[t] * rsqrtf(v0[t] + EPSV);
    sc[t] = s;
    sh[t] = b0[t] - m0[t] * s;
  }
  __syncthreads();
  const float* xp = x + (size_t)n * 64 * HWp + h * Wimg;
  for (int i = t; i < 64 * Wimg; i += 256) {
    int c = i / Wimg, w = i - c * Wimg;
    tile[c][w] = xp[(size_t)c * HWp + w] * sc[c] + sh[c];
  }
  __syncthreads();
  unsigned short* op = x0 + (size_t)bid * Wimg * 64;
  for (int i = t * 4; i < Wimg * 64; i += 1024) {
    int w = i >> 6, c = i & 63;
    u16x4 u;
    u[0] = f2bf(tile[c + 0][w]);
    u[1] = f2bf(tile[c + 1][w]);
    u[2] = f2bf(tile[c + 2][w]);
    u[3] = f2bf(tile[c + 3][w]);
    *reinterpret_cast<u16x4*>(op + i) = u;
  }
}

// ---------------------------------------------------------------------------
// conv3x3p<STAGE>: grid-persistent implicit-GEMM 3x3 conv (R6 structure).
//   grid 256 (1 block/CU), 448 thr = 7 waves; block owns image n=b>>2,
//   rows [q*28, q*28+28), 7 tiles of 4 rows x 112 w x 64 co.
//   LDS (161280 B): ring 6 x [114][128B] XOR-swz + weights [18][4][1024B] once.
//   Both stages: mfma(wf, pf) -> D[co][pixel] (R11's swapped variant hurt).
//   STAGE 2 NEW: resid loads (64 scalars/thread) issued at TILE START into
//   registers (T14), pinned with sched_barrier(0) so they drain under the
//   K-loop; epilogue is compute+store only. (R6/R11 issued them inside the
//   epilogue: latency + drain fully exposed in the serial phase -> HBM duty
//   cycle ~50%, achieved ~3 TB/s.)
// ---------------------------------------------------------------------------
template <int STAGE>
__global__ __launch_bounds__(448, 2) void conv3x3p(
    const unsigned short* __restrict__ src,   // bf16 NHWC [P][64]
    const unsigned short* __restrict__ wP,    // packed bf16 fragments (73728 B)
    const float* __restrict__ scale, const float* __restrict__ shift,
    const float* __restrict__ aP,
    unsigned short* __restrict__ dstb,        // STAGE 1 out
    float* __restrict__ dstf,                 // STAGE 2 out
    const float* __restrict__ resid)          // STAGE 2 residual
{
  constexpr int RS   = 114 * 128;   // 14592 B per row-slot
  constexpr int WOFF = 6 * RS;      // 87552
  __shared__ __align__(16) unsigned char lds[WOFF + 73728];  // 161280 B

  const int t = threadIdx.x;
  const int b = blockIdx.x;
  const int n = b >> 2, q = b & 3;
  const int qbase = q * 28;
  const size_t ibase = (size_t)n * HWp;

  const int wv = t >> 6, l = t & 63;
  const int lo = l & 15, grp = l >> 4;

  // ---------------- prologue ----------------
  // weights: 4608 x 16B chunks, linear
#pragma unroll
  for (int it = 0; it < 11; ++it) {
    int idx = t + it * 448;
    if (it < 10 || idx < 4608) {
      u32x4 v = *reinterpret_cast<const u32x4*>(wP + idx * 8);
      *reinterpret_cast<u32x4*>(&lds[WOFF + idx * 16]) = v;
    }
  }
  // wpad zero columns (P=0,113) for all 6 slots — written once, never dirtied
  if (t < 96) {
    int r = t >> 4, P = ((t >> 3) & 1) ? 113 : 0, k = t & 7;
    u32x4 z = {0u, 0u, 0u, 0u};
    *reinterpret_cast<u32x4*>(&lds[r * RS + P * 128 + ((k ^ (P & 7)) << 4)]) = z;
  }
  // patch rows qbase-1 .. qbase+4 into slots 0..5
#pragma unroll
  for (int it = 0; it < 12; ++it) {
    int r = it >> 1;                       // compile-time row index
    int rem = t + (it & 1) * 448;
    int w = rem >> 3, k = rem & 7;
    int hh = qbase - 1 + r;
    u32x4 val = {0u, 0u, 0u, 0u};
    if ((unsigned)hh < 112u)
      val = *reinterpret_cast<const u32x4*>(src + (ibase + hh * Wimg + w) * 64 + k * 8);
    int P = w + 1;
    *reinterpret_cast<u32x4*>(&lds[r * RS + P * 128 + ((k ^ (P & 7)) << 4)]) = val;
  }
  __syncthreads();

  int rb0 = 0 * RS, rb1 = 1 * RS, rb2 = 2 * RS, rb3 = 3 * RS, rb4 = 4 * RS, rb5 = 5 * RS;

  for (int T = 0; T < 7; ++T) {
    const int r0 = qbase + T * 4;

    // ---- T14a: prefetch this tile's resid into regs (STAGE 2 only) ----
    float rres[4][4][4];
    if (STAGE == 2) {
#pragma unroll
      for (int c = 0; c < 4; ++c) {
        const int co0 = c * 16 + grp * 4;
#pragma unroll
        for (int p = 0; p < 4; ++p) {
          const int hh = r0 + p;
#pragma unroll
          for (int j = 0; j < 4; ++j) {
            size_t idx = ((size_t)(n * 64 + co0 + j) * Himg + hh) * Wimg + wv * 16 + lo;
            rres[c][p][j] = resid[idx];
          }
        }
      }
    }

    // ---- T14b: prefetch next tile's 4 input rows (global -> regs) ----
    u32x4 preg[8];
    if (T < 6) {
#pragma unroll
      for (int it = 0; it < 8; ++it) {
        int j = it >> 1;                   // compile-time
        int rem = t + (it & 1) * 448;
        int w = rem >> 3, k = rem & 7;
        int hh = r0 + 5 + j;
        u32x4 val = {0u, 0u, 0u, 0u};
        if (hh < 112)
          val = *reinterpret_cast<const u32x4*>(src + (ibase + hh * Wimg + w) * 64 + k * 8);
        preg[it] = val;
      }
    }
    // pin: prefetches may not sink below; K-loop stays below
    __builtin_amdgcn_sched_barrier(0);

    f32x4 acc[4][4];
#pragma unroll
    for (int c = 0; c < 4; ++c)
#pragma unroll
      for (int p = 0; p < 4; ++p) {
        f32x4 z = {0.f, 0.f, 0.f, 0.f};
        acc[c][p] = z;
      }

    // ---- K-loop: 18 steps, pure LDS + MFMA ----
#pragma unroll
    for (int s = 0; s < 18; ++s) {
      const int tap = s >> 1, ks = s & 1;
      const int dh = tap / 3, dw = tap - dh * 3;
      bf16x8 wf[4], pf[4];
#pragma unroll
      for (int c = 0; c < 4; ++c)
        wf[c] = *reinterpret_cast<const bf16x8*>(&lds[WOFF + (s * 4 + c) * 1024 + l * 16]);
      const int Pr = wv * 16 + lo + dw;
      const int c8 = (ks << 2) | grp;
      const int pbyte = Pr * 128 + ((c8 ^ (Pr & 7)) << 4);
#pragma unroll
      for (int p = 0; p < 4; ++p) {
        const int rr = p + dh;             // compile-time 0..5
        const int rbr = (rr == 0) ? rb0 : (rr == 1) ? rb1 : (rr == 2) ? rb2
                      : (rr == 3) ? rb3 : (rr == 4) ? rb4 : rb5;
        pf[p] = *reinterpret_cast<const bf16x8*>(&lds[rbr + pbyte]);
      }
#pragma unroll
      for (int c = 0; c < 4; ++c)
#pragma unroll
        for (int p = 0; p < 4; ++p)
          acc[c][p] = __builtin_amdgcn_mfma_f32_16x16x32_bf16(wf[c], pf[p], acc[c][p], 0, 0, 0);
    }

    // ---- epilogue (R6 order: before the restage barriers) ----
#pragma unroll
    for (int c = 0; c < 4; ++c) {
      const int co0 = c * 16 + grp * 4;
      float s_[4], h_[4], a_[4];
#pragma unroll
      for (int j = 0; j < 4; ++j) {
        s_[j] = scale[co0 + j];
        h_[j] = shift[co0 + j];
        a_[j] = aP[co0 + j];
      }
      const int w = wv * 16 + lo;
#pragma unroll
      for (int p = 0; p < 4; ++p) {
        const int hh = r0 + p;
        f32x4 v = acc[c][p];
        if (STAGE == 1) {
          u16x4 u;
#pragma unroll
          for (int j = 0; j < 4; ++j) {
            float vv = v[j] * s_[j] + h_[j];
            vv = vv >= 0.f ? vv : vv * a_[j];
            u[j] = f2bf(vv);
          }
          *reinterpret_cast<u16x4*>(dstb + (ibase + hh * Wimg + w) * 64 + co0) = u;
        } else {
#pragma unroll
          for (int j = 0; j < 4; ++j) {
            size_t idx = ((size_t)(n * 64 + co0 + j) * Himg + hh) * Wimg + w;
            float vv = v[j] * s_[j] + h_[j] + rres[c][p][j];
            vv = vv >= 0.f ? vv : vv * a_[j];
            dstf[idx] = vv;
          }
        }
      }
    }

    // ---- restage ring (R6 order) ----
    if (T < 6) {
      __syncthreads();   // all waves done reading slots about to be overwritten
#pragma unroll
      for (int it = 0; it < 8; ++it) {
        int j = it >> 1;                   // compile-time
        int rem = t + (it & 1) * 448;
        int w = rem >> 3, k = rem & 7;
        int P = w + 1;
        const int dst = (j == 0) ? rb0 : (j == 1) ? rb1 : (j == 2) ? rb2 : rb3;
        *reinterpret_cast<u32x4*>(&lds[dst + P * 128 + ((k ^ (P & 7)) << 4)]) = preg[it];
      }
      __syncthreads();
    }

    // rotate ring by 4 rows: new(0..5) = old(4,5,0,1,2,3)
    int n0 = rb4, n1 = rb5, n2 = rb0, n3 = rb1, n4 = rb2, n5 = rb3;
    rb0 = n0; rb1 = n1; rb2 = n2; rb3 = n3; rb4 = n4; rb5 = n5;
  }
}

// ---------------------------------------------------------------------------
// scratch map:
//   d_out[0 .. 102,760,448)     : x0 bf16 NHWC (dead before conv2 writes)
//   d_ws [0 .. 102,760,448)     : y1 bf16 NHWC
//   d_ws [+0 .. +73,728)        : wt1 packed bf16
//   d_ws [+73,728 .. +147,456)  : wt2 packed bf16
//   d_ws [+147,456 .. +148,480) : prm f32
// ---------------------------------------------------------------------------
extern "C" void kernel_launch(void* const* d_in, const int* in_sizes, int n_in,
                              void* d_out, int out_size, void* d_ws, size_t ws_size,
                              hipStream_t stream)
{
  const float* x  = (const float*)d_in[0];
  const float* w1 = (const float*)d_in[1];
  const float* w2 = (const float*)d_in[2];
  const float* g0 = (const float*)d_in[3];
  const float* b0 = (const float*)d_in[4];
  const float* m0 = (const float*)d_in[5];
  const float* v0 = (const float*)d_in[6];
  const float* g1 = (const float*)d_in[7];
  const float* b1 = (const float*)d_in[8];
  const float* m1 = (const float*)d_in[9];
  const float* v1 = (const float*)d_in[10];
  const float* g2 = (const float*)d_in[11];
  const float* b2 = (const float*)d_in[12];
  const float* m2 = (const float*)d_in[13];
  const float* v2 = (const float*)d_in[14];
  const float* a1 = (const float*)d_in[15];
  const float* a2 = (const float*)d_in[16];

  unsigned short* x0 = (unsigned short*)d_out;
  unsigned char* wsb = (unsigned char*)d_ws;
  unsigned short* y1  = (unsigned short*)wsb;
  unsigned short* wt1 = (unsigned short*)(wsb + 102760448);
  unsigned short* wt2 = (unsigned short*)(wsb + 102760448 + 73728);
  float* prm          = (float*)(wsb + 102760448 + 2 * 73728);

  prep_misc<<<16, 256, 0, stream>>>(w1, w2, g1, b1, m1, v1, g2, b2, m2, v2, wt1, wt2, prm);
  prep_x0<<<64 * 112, 256, 0, stream>>>(x, g0, b0, m0, v0, x0);
  conv3x3p<1><<<256, 448, 0, stream>>>(x0, wt1, prm, prm + 64, a1, y1, nullptr, nullptr);
  conv3x3p<2><<<256, 448, 0, stream>>>(y1, wt2, prm + 128, prm + 192, a2, nullptr, (float*)d_out, x);
}

// Round 13
// 378.810 us; speedup vs baseline: 1.0008x; 1.0008x over previous
//
#include <hip/hip_runtime.h>

#define EPSV 1e-5f

typedef __bf16 bf16x8 __attribute__((ext_vector_type(8)));
typedef float f32x4 __attribute__((ext_vector_type(4)));
typedef unsigned int u32x4 __attribute__((ext_vector_type(4)));
typedef unsigned short u16x4 __attribute__((ext_vector_type(4)));

__device__ __forceinline__ unsigned short f2bf(float f) {
  return __builtin_bit_cast(unsigned short, static_cast<__bf16>(f));
}

constexpr int Himg = 112, Wimg = 112, HWp = Himg * Wimg;  // 12544

// ---------------------------------------------------------------------------
// prep_misc: pack weights into per-lane MFMA A-fragment order + BN scale/shift.
//   wPack[i], i = ((tap*2+ks)*4 + c)*512 + l*8 + j  (bf16)
//   co = c*16+(l&15), ci = ks*32+(l>>4)*8+j
// ---------------------------------------------------------------------------
__global__ __launch_bounds__(256) void prep_misc(
    const float* __restrict__ w1, const float* __restrict__ w2,
    const float* __restrict__ g1, const float* __restrict__ b1,
    const float* __restrict__ m1, const float* __restrict__ v1,
    const float* __restrict__ g2, const float* __restrict__ b2,
    const float* __restrict__ m2, const float* __restrict__ v2,
    unsigned short* __restrict__ wt1, unsigned short* __restrict__ wt2,
    float* __restrict__ prm)
{
  int id = blockIdx.x * 256 + threadIdx.x;
  for (int i = id; i < 9 * 2 * 4 * 512; i += gridDim.x * 256) {
    int j   = i & 7;
    int l   = (i >> 3) & 63;
    int c   = (i >> 9) & 3;
    int ks  = (i >> 11) & 1;
    int tap = i >> 12;
    int co  = c * 16 + (l & 15);
    int ci  = ks * 32 + (l >> 4) * 8 + j;
    int kh  = tap / 3, kw = tap - kh * 3;
    int src = ((co * 64 + ci) * 3 + kh) * 3 + kw;
    wt1[i] = f2bf(w1[src]);
    wt2[i] = f2bf(w2[src]);
  }
  if (id < 64) {
    float s1 = g1[id] * rsqrtf(v1[id] + EPSV);
    prm[id]      = s1;
    prm[64 + id] = b1[id] - m1[id] * s1;
    float s2 = g2[id] * rsqrtf(v2[id] + EPSV);
    prm[128 + id] = s2;
    prm[192 + id] = b2[id] - m2[id] * s2;
  }
}

// ---------------------------------------------------------------------------
// prep_x0: x NCHW f32 -> x0 = BN0(x) as NHWC bf16
// ---------------------------------------------------------------------------
__global__ __launch_bounds__(256) void prep_x0(
    const float* __restrict__ x,
    const float* __restrict__ g0, const float* __restrict__ b0,
    const float* __restrict__ m0, const float* __restrict__ v0,
    unsigned short* __restrict__ x0)
{
  __shared__ float sc[64];
  __shared__ float sh[64];
  __shared__ float tile[64][113];
  const int t = threadIdx.x;
  const int bid = blockIdx.x;          // n*112 + h
  const int n = bid / 112, h = bid - n * 112;
  if (t < 64) {
    float s = g0[t] * rsqrtf(v0[t] + EPSV);
    sc[t] = s;
    sh[t] = b0[t] - m0[t] * s;
  }
  __syncthreads();
  const float* xp = x + (size_t)n * 64 * HWp + h * Wimg;
  for (int i = t; i < 64 * Wimg; i += 256) {
    int c = i / Wimg, w = i - c * Wimg;
    tile[c][w] = xp[(size_t)c * HWp + w] * sc[c] + sh[c];
  }
  __syncthreads();
  unsigned short* op = x0 + (size_t)bid * Wimg * 64;
  for (int i = t * 4; i < Wimg * 64; i += 1024) {
    int w = i >> 6, c = i & 63;
    u16x4 u;
    u[0] = f2bf(tile[c + 0][w]);
    u[1] = f2bf(tile[c + 1][w]);
    u[2] = f2bf(tile[c + 2][w]);
    u[3] = f2bf(tile[c + 3][w]);
    *reinterpret_cast<u16x4*>(op + i) = u;
  }
}

// ---------------------------------------------------------------------------
// conv3x3p<STAGE>: grid-persistent implicit-GEMM 3x3 conv (R6 structure).
//   grid 256 (1 block/CU), 448 thr = 7 waves; block owns image n=b>>2,
//   rows [q*28, q*28+28), 7 tiles of 4 rows x 112 w x 64 co.
//   LDS (161280 B): ring 6 x [114][128B] XOR-swz + weights [18][4][1024B] once.
//   __launch_bounds__(448, 1): 7 waves -> <=2/SIMD -> 256-VGPR cap.
//   ((448,2) forced budgeting for 2 blocks = 4 waves/SIMD = 128-VGPR cap,
//    which spilled R12's resid prefetch; LDS allows only 1 block anyway.)
//   STAGE 2: resid loads (64/thread) issued at TILE START into regs (T14),
//   pinned with sched_barrier(0); they drain under the K-loop.
// ---------------------------------------------------------------------------
template <int STAGE>
__global__ __launch_bounds__(448, 1) void conv3x3p(
    const unsigned short* __restrict__ src,   // bf16 NHWC [P][64]
    const unsigned short* __restrict__ wP,    // packed bf16 fragments (73728 B)
    const float* __restrict__ scale, const float* __restrict__ shift,
    const float* __restrict__ aP,
    unsigned short* __restrict__ dstb,        // STAGE 1 out
    float* __restrict__ dstf,                 // STAGE 2 out
    const float* __restrict__ resid)          // STAGE 2 residual
{
  constexpr int RS   = 114 * 128;   // 14592 B per row-slot
  constexpr int WOFF = 6 * RS;      // 87552
  __shared__ __align__(16) unsigned char lds[WOFF + 73728];  // 161280 B

  const int t = threadIdx.x;
  const int b = blockIdx.x;
  const int n = b >> 2, q = b & 3;
  const int qbase = q * 28;
  const size_t ibase = (size_t)n * HWp;

  const int wv = t >> 6, l = t & 63;
  const int lo = l & 15, grp = l >> 4;

  // ---------------- prologue ----------------
  // weights: 4608 x 16B chunks, linear
#pragma unroll
  for (int it = 0; it < 11; ++it) {
    int idx = t + it * 448;
    if (it < 10 || idx < 4608) {
      u32x4 v = *reinterpret_cast<const u32x4*>(wP + idx * 8);
      *reinterpret_cast<u32x4*>(&lds[WOFF + idx * 16]) = v;
    }
  }
  // wpad zero columns (P=0,113) for all 6 slots — written once, never dirtied
  if (t < 96) {
    int r = t >> 4, P = ((t >> 3) & 1) ? 113 : 0, k = t & 7;
    u32x4 z = {0u, 0u, 0u, 0u};
    *reinterpret_cast<u32x4*>(&lds[r * RS + P * 128 + ((k ^ (P & 7)) << 4)]) = z;
  }
  // patch rows qbase-1 .. qbase+4 into slots 0..5
#pragma unroll
  for (int it = 0; it < 12; ++it) {
    int r = it >> 1;                       // compile-time row index
    int rem = t + (it & 1) * 448;
    int w = rem >> 3, k = rem & 7;
    int hh = qbase - 1 + r;
    u32x4 val = {0u, 0u, 0u, 0u};
    if ((unsigned)hh < 112u)
      val = *reinterpret_cast<const u32x4*>(src + (ibase + hh * Wimg + w) * 64 + k * 8);
    int P = w + 1;
    *reinterpret_cast<u32x4*>(&lds[r * RS + P * 128 + ((k ^ (P & 7)) << 4)]) = val;
  }
  __syncthreads();

  int rb0 = 0 * RS, rb1 = 1 * RS, rb2 = 2 * RS, rb3 = 3 * RS, rb4 = 4 * RS, rb5 = 5 * RS;

  for (int T = 0; T < 7; ++T) {
    const int r0 = qbase + T * 4;

    // ---- T14a: prefetch this tile's resid into regs (STAGE 2 only) ----
    float rres[4][4][4];
    if (STAGE == 2) {
#pragma unroll
      for (int c = 0; c < 4; ++c) {
        const int co0 = c * 16 + grp * 4;
#pragma unroll
        for (int p = 0; p < 4; ++p) {
          const int hh = r0 + p;
#pragma unroll
          for (int j = 0; j < 4; ++j) {
            size_t idx = ((size_t)(n * 64 + co0 + j) * Himg + hh) * Wimg + wv * 16 + lo;
            rres[c][p][j] = resid[idx];
          }
        }
      }
    }

    // ---- T14b: prefetch next tile's 4 input rows (global -> regs) ----
    u32x4 preg[8];
    if (T < 6) {
#pragma unroll
      for (int it = 0; it < 8; ++it) {
        int j = it >> 1;                   // compile-time
        int rem = t + (it & 1) * 448;
        int w = rem >> 3, k = rem & 7;
        int hh = r0 + 5 + j;
        u32x4 val = {0u, 0u, 0u, 0u};
        if (hh < 112)
          val = *reinterpret_cast<const u32x4*>(src + (ibase + hh * Wimg + w) * 64 + k * 8);
        preg[it] = val;
      }
    }
    // pin: prefetches may not sink below; K-loop stays below
    __builtin_amdgcn_sched_barrier(0);

    f32x4 acc[4][4];
#pragma unroll
    for (int c = 0; c < 4; ++c)
#pragma unroll
      for (int p = 0; p < 4; ++p) {
        f32x4 z = {0.f, 0.f, 0.f, 0.f};
        acc[c][p] = z;
      }

    // ---- K-loop: 18 steps, pure LDS + MFMA ----
#pragma unroll
    for (int s = 0; s < 18; ++s) {
      const int tap = s >> 1, ks = s & 1;
      const int dh = tap / 3, dw = tap - dh * 3;
      bf16x8 wf[4], pf[4];
#pragma unroll
      for (int c = 0; c < 4; ++c)
        wf[c] = *reinterpret_cast<const bf16x8*>(&lds[WOFF + (s * 4 + c) * 1024 + l * 16]);
      const int Pr = wv * 16 + lo + dw;
      const int c8 = (ks << 2) | grp;
      const int pbyte = Pr * 128 + ((c8 ^ (Pr & 7)) << 4);
#pragma unroll
      for (int p = 0; p < 4; ++p) {
        const int rr = p + dh;             // compile-time 0..5
        const int rbr = (rr == 0) ? rb0 : (rr == 1) ? rb1 : (rr == 2) ? rb2
                      : (rr == 3) ? rb3 : (rr == 4) ? rb4 : rb5;
        pf[p] = *reinterpret_cast<const bf16x8*>(&lds[rbr + pbyte]);
      }
#pragma unroll
      for (int c = 0; c < 4; ++c)
#pragma unroll
        for (int p = 0; p < 4; ++p)
          acc[c][p] = __builtin_amdgcn_mfma_f32_16x16x32_bf16(wf[c], pf[p], acc[c][p], 0, 0, 0);
    }

    // ---- epilogue (R6 order: before the restage barriers) ----
#pragma unroll
    for (int c = 0; c < 4; ++c) {
      const int co0 = c * 16 + grp * 4;
      float s_[4], h_[4], a_[4];
#pragma unroll
      for (int j = 0; j < 4; ++j) {
        s_[j] = scale[co0 + j];
        h_[j] = shift[co0 + j];
        a_[j] = aP[co0 + j];
      }
      const int w = wv * 16 + lo;
#pragma unroll
      for (int p = 0; p < 4; ++p) {
        const int hh = r0 + p;
        f32x4 v = acc[c][p];
        if (STAGE == 1) {
          u16x4 u;
#pragma unroll
          for (int j = 0; j < 4; ++j) {
            float vv = v[j] * s_[j] + h_[j];
            vv = vv >= 0.f ? vv : vv * a_[j];
            u[j] = f2bf(vv);
          }
          *reinterpret_cast<u16x4*>(dstb + (ibase + hh * Wimg + w) * 64 + co0) = u;
        } else {
#pragma unroll
          for (int j = 0; j < 4; ++j) {
            size_t idx = ((size_t)(n * 64 + co0 + j) * Himg + hh) * Wimg + w;
            float vv = v[j] * s_[j] + h_[j] + rres[c][p][j];
            vv = vv >= 0.f ? vv : vv * a_[j];
            dstf[idx] = vv;
          }
        }
      }
    }

    // ---- restage ring (R6 order) ----
    if (T < 6) {
      __syncthreads();   // all waves done reading slots about to be overwritten
#pragma unroll
      for (int it = 0; it < 8; ++it) {
        int j = it >> 1;                   // compile-time
        int rem = t + (it & 1) * 448;
        int w = rem >> 3, k = rem & 7;
        int P = w + 1;
        const int dst = (j == 0) ? rb0 : (j == 1) ? rb1 : (j == 2) ? rb2 : rb3;
        *reinterpret_cast<u32x4*>(&lds[dst + P * 128 + ((k ^ (P & 7)) << 4)]) = preg[it];
      }
      __syncthreads();
    }

    // rotate ring by 4 rows: new(0..5) = old(4,5,0,1,2,3)
    int n0 = rb4, n1 = rb5, n2 = rb0, n3 = rb1, n4 = rb2, n5 = rb3;
    rb0 = n0; rb1 = n1; rb2 = n2; rb3 = n3; rb4 = n4; rb5 = n5;
  }
}

// ---------------------------------------------------------------------------
// scratch map:
//   d_out[0 .. 102,760,448)     : x0 bf16 NHWC (dead before conv2 writes)
//   d_ws [0 .. 102,760,448)     : y1 bf16 NHWC
//   d_ws [+0 .. +73,728)        : wt1 packed bf16
//   d_ws [+73,728 .. +147,456)  : wt2 packed bf16
//   d_ws [+147,456 .. +148,480) : prm f32
// ---------------------------------------------------------------------------
extern "C" void kernel_launch(void* const* d_in, const int* in_sizes, int n_in,
                              void* d_out, int out_size, void* d_ws, size_t ws_size,
                              hipStream_t stream)
{
  const float* x  = (const float*)d_in[0];
  const float* w1 = (const float*)d_in[1];
  const float* w2 = (const float*)d_in[2];
  const float* g0 = (const float*)d_in[3];
  const float* b0 = (const float*)d_in[4];
  const float* m0 = (const float*)d_in[5];
  const float* v0 = (const float*)d_in[6];
  const float* g1 = (const float*)d_in[7];
  const float* b1 = (const float*)d_in[8];
  const float* m1 = (const float*)d_in[9];
  const float* v1 = (const float*)d_in[10];
  const float* g2 = (const float*)d_in[11];
  const float* b2 = (const float*)d_in[12];
  const float* m2 = (const float*)d_in[13];
  const float* v2 = (const float*)d_in[14];
  const float* a1 = (const float*)d_in[15];
  const float* a2 = (const float*)d_in[16];

  unsigned short* x0 = (unsigned short*)d_out;
  unsigned char* wsb = (unsigned char*)d_ws;
  unsigned short* y1  = (unsigned short*)wsb;
  unsigned short* wt1 = (unsigned short*)(wsb + 102760448);
  unsigned short* wt2 = (unsigned short*)(wsb + 102760448 + 73728);
  float* prm          = (float*)(wsb + 102760448 + 2 * 73728);

  prep_misc<<<16, 256, 0, stream>>>(w1, w2, g1, b1, m1, v1, g2, b2, m2, v2, wt1, wt2, prm);
  prep_x0<<<64 * 112, 256, 0, stream>>>(x, g0, b0, m0, v0, x0);
  conv3x3p<1><<<256, 448, 0, stream>>>(x0, wt1, prm, prm + 64, a1, y1, nullptr, nullptr);
  conv3x3p<2><<<256, 448, 0, stream>>>(y1, wt2, prm + 128, prm + 192, a2, nullptr, (float*)d_out, x);
}

// Round 14
// 264.193 us; speedup vs baseline: 1.4350x; 1.4338x over previous
//
#include <hip/hip_runtime.h>

#define EPSV 1e-5f

typedef __bf16 bf16x8 __attribute__((ext_vector_type(8)));
typedef float f32x4 __attribute__((ext_vector_type(4)));
typedef unsigned int u32x4 __attribute__((ext_vector_type(4)));
typedef unsigned short u16x4 __attribute__((ext_vector_type(4)));

__device__ __forceinline__ unsigned short f2bf(float f) {
  return __builtin_bit_cast(unsigned short, static_cast<__bf16>(f));
}

constexpr int Himg = 112, Wimg = 112, HWp = Himg * Wimg;  // 12544

// ---------------------------------------------------------------------------
// prep_misc: pack weights into per-lane MFMA A-fragment order + BN scale/shift
//   for ALL THREE BNs (BN0 now consumed by conv1's fused staging).
//   prm: [0)=s1 [64)=h1 [128)=s2 [192)=h2 [256)=s0 [320)=h0
// ---------------------------------------------------------------------------
__global__ __launch_bounds__(256) void prep_misc(
    const float* __restrict__ w1, const float* __restrict__ w2,
    const float* __restrict__ g0, const float* __restrict__ b0,
    const float* __restrict__ m0, const float* __restrict__ v0,
    const float* __restrict__ g1, const float* __restrict__ b1,
    const float* __restrict__ m1, const float* __restrict__ v1,
    const float* __restrict__ g2, const float* __restrict__ b2,
    const float* __restrict__ m2, const float* __restrict__ v2,
    unsigned short* __restrict__ wt1, unsigned short* __restrict__ wt2,
    float* __restrict__ prm)
{
  int id = blockIdx.x * 256 + threadIdx.x;
  for (int i = id; i < 9 * 2 * 4 * 512; i += gridDim.x * 256) {
    int j   = i & 7;
    int l   = (i >> 3) & 63;
    int c   = (i >> 9) & 3;
    int ks  = (i >> 11) & 1;
    int tap = i >> 12;
    int co  = c * 16 + (l & 15);
    int ci  = ks * 32 + (l >> 4) * 8 + j;
    int kh  = tap / 3, kw = tap - kh * 3;
    int src = ((co * 64 + ci) * 3 + kh) * 3 + kw;
    wt1[i] = f2bf(w1[src]);
    wt2[i] = f2bf(w2[src]);
  }
  if (id < 64) {
    float s1 = g1[id] * rsqrtf(v1[id] + EPSV);
    prm[id]      = s1;
    prm[64 + id] = b1[id] - m1[id] * s1;
    float s2 = g2[id] * rsqrtf(v2[id] + EPSV);
    prm[128 + id] = s2;
    prm[192 + id] = b2[id] - m2[id] * s2;
    float s0 = g0[id] * rsqrtf(v0[id] + EPSV);
    prm[256 + id] = s0;
    prm[320 + id] = b0[id] - m0[id] * s0;
  }
}

// ---------------------------------------------------------------------------
// conv3x3p<STAGE>: grid-persistent implicit-GEMM 3x3 conv (R6 structure).
//   grid 256 (1 block/CU), 448 thr = 7 waves; block owns image n=b>>2,
//   rows [q*28, q*28+28), 7 tiles of 4 rows x 112 w x 64 co.
//   LDS (161280 B): ring 6 x [114][128B] XOR-swz + weights [18][4][1024B] once.
//   STAGE 1: sources x (NCHW f32) directly — BN0 fused into staging
//     (prep_x0 kernel eliminated: −305 MB HBM). Thread map (cs=t/28, wb=t%28):
//     per row per unit u: 2 f32x4 loads (planes cs*4+2u, +1) -> BN0 ->
//     bf16-pair pack -> 4 ds_write_b32 into the swizzled layout.
//     Prefetch 2 of the next 4 rows into regs (32 VGPR, R6 budget);
//     other 2 loaded directly at restage (R12/R13 lesson: no big reg arrays).
//   STAGE 2: byte-for-byte R6 (y1 NHWC u32x4 staging; epilogue with inline
//     resid loads — every prefetch variant spilled or regressed).
// ---------------------------------------------------------------------------
template <int STAGE>
__global__ __launch_bounds__(448, 2) void conv3x3p(
    const unsigned short* __restrict__ src,   // STAGE 2: y1 bf16 NHWC
    const float* __restrict__ xsrc,           // STAGE 1: x f32 NCHW
    const unsigned short* __restrict__ wP,    // packed bf16 fragments (73728 B)
    const float* __restrict__ scale, const float* __restrict__ shift,
    const float* __restrict__ aP,
    const float* __restrict__ bn0sc, const float* __restrict__ bn0sh,
    unsigned short* __restrict__ dstb,        // STAGE 1 out (y1)
    float* __restrict__ dstf,                 // STAGE 2 out
    const float* __restrict__ resid)          // STAGE 2 residual
{
  constexpr int RS   = 114 * 128;   // 14592 B per row-slot
  constexpr int WOFF = 6 * RS;      // 87552
  __shared__ __align__(16) unsigned char lds[WOFF + 73728];  // 161280 B

  const int t = threadIdx.x;
  const int b = blockIdx.x;
  const int n = b >> 2, q = b & 3;
  const int qbase = q * 28;
  const size_t ibase = (size_t)n * HWp;
  const float* xn = xsrc ? xsrc + (size_t)n * 64 * HWp : nullptr;

  const int wv = t >> 6, l = t & 63;
  const int lo = l & 15, grp = l >> 4;

  // stage-1 staging map + BN0 constants
  const int cs = t / 28, wb = t - cs * 28;
  const int w0s = wb * 4;
  float scv[4], shv[4];
  if (STAGE == 1) {
#pragma unroll
    for (int cc = 0; cc < 4; ++cc) {
      scv[cc] = bn0sc[cs * 4 + cc];
      shv[cc] = bn0sh[cs * 4 + cc];
    }
  }

  // helpers for stage-1 x->LDS staging (BN0 + bf16 pack, swizzled layout)
  auto load_rowx = [&](int hh, f32x4 (&A)[2], f32x4 (&B)[2]) -> bool {
    bool valid = (unsigned)hh < 112u;
#pragma unroll
    for (int u = 0; u < 2; ++u) {
      f32x4 z = {0.f, 0.f, 0.f, 0.f};
      A[u] = z; B[u] = z;
      if (valid) {
        const int ca = cs * 4 + u * 2;
        A[u] = *reinterpret_cast<const f32x4*>(xn + (size_t)ca * HWp + hh * Wimg + w0s);
        B[u] = *reinterpret_cast<const f32x4*>(xn + (size_t)(ca + 1) * HWp + hh * Wimg + w0s);
      }
    }
    return valid;
  };
  auto emit_rowx = [&](int rbX, const f32x4 (&A)[2], const f32x4 (&B)[2], bool valid) {
#pragma unroll
    for (int u = 0; u < 2; ++u) {
      const int ca = cs * 4 + u * 2;
      const int kk = ca >> 3;
      const int off = (ca & 7) * 2;
#pragma unroll
      for (int j = 0; j < 4; ++j) {
        float fa = valid ? A[u][j] * scv[u * 2] + shv[u * 2] : 0.f;
        float fb = valid ? B[u][j] * scv[u * 2 + 1] + shv[u * 2 + 1] : 0.f;
        unsigned int pk = (unsigned int)f2bf(fa) | ((unsigned int)f2bf(fb) << 16);
        int P = w0s + j + 1;
        *reinterpret_cast<unsigned int*>(
            &lds[rbX + P * 128 + ((kk ^ (P & 7)) << 4) + off]) = pk;
      }
    }
  };

  // ---------------- prologue ----------------
  // weights: 4608 x 16B chunks, linear
#pragma unroll
  for (int it = 0; it < 11; ++it) {
    int idx = t + it * 448;
    if (it < 10 || idx < 4608) {
      u32x4 v = *reinterpret_cast<const u32x4*>(wP + idx * 8);
      *reinterpret_cast<u32x4*>(&lds[WOFF + idx * 16]) = v;
    }
  }
  // wpad zero columns (P=0,113) for all 6 slots — written once, never dirtied
  if (t < 96) {
    int r = t >> 4, P = ((t >> 3) & 1) ? 113 : 0, k = t & 7;
    u32x4 z = {0u, 0u, 0u, 0u};
    *reinterpret_cast<u32x4*>(&lds[r * RS + P * 128 + ((k ^ (P & 7)) << 4)]) = z;
  }
  // patch rows qbase-1 .. qbase+4 into slots 0..5
  if (STAGE == 1) {
#pragma unroll
    for (int r = 0; r < 6; ++r) {
      f32x4 A[2], B[2];
      bool v = load_rowx(qbase - 1 + r, A, B);
      emit_rowx(r * RS, A, B, v);
    }
  } else {
#pragma unroll
    for (int it = 0; it < 12; ++it) {
      int r = it >> 1;                       // compile-time row index
      int rem = t + (it & 1) * 448;
      int w = rem >> 3, k = rem & 7;
      int hh = qbase - 1 + r;
      u32x4 val = {0u, 0u, 0u, 0u};
      if ((unsigned)hh < 112u)
        val = *reinterpret_cast<const u32x4*>(src + (ibase + hh * Wimg + w) * 64 + k * 8);
      int P = w + 1;
      *reinterpret_cast<u32x4*>(&lds[r * RS + P * 128 + ((k ^ (P & 7)) << 4)]) = val;
    }
  }
  __syncthreads();

  int rb0 = 0 * RS, rb1 = 1 * RS, rb2 = 2 * RS, rb3 = 3 * RS, rb4 = 4 * RS, rb5 = 5 * RS;

  for (int T = 0; T < 7; ++T) {
    const int r0 = qbase + T * 4;

    // ---- T14: prefetch next tile's rows (global -> regs) ----
    u32x4 preg[8];                // STAGE 2: 4 rows
    f32x4 pA[2][2], pB[2][2];     // STAGE 1: 2 rows raw f32
    bool pv[2];
    if (T < 6) {
      if (STAGE == 1) {
#pragma unroll
        for (int rr = 0; rr < 2; ++rr)
          pv[rr] = load_rowx(r0 + 5 + rr, pA[rr], pB[rr]);
      } else {
#pragma unroll
        for (int it = 0; it < 8; ++it) {
          int j = it >> 1;                   // compile-time
          int rem = t + (it & 1) * 448;
          int w = rem >> 3, k = rem & 7;
          int hh = r0 + 5 + j;
          u32x4 val = {0u, 0u, 0u, 0u};
          if (hh < 112)
            val = *reinterpret_cast<const u32x4*>(src + (ibase + hh * Wimg + w) * 64 + k * 8);
          preg[it] = val;
        }
      }
    }

    f32x4 acc[4][4];
#pragma unroll
    for (int c = 0; c < 4; ++c)
#pragma unroll
      for (int p = 0; p < 4; ++p) {
        f32x4 z = {0.f, 0.f, 0.f, 0.f};
        acc[c][p] = z;
      }

    // ---- K-loop: 18 steps, pure LDS + MFMA ----
#pragma unroll
    for (int s = 0; s < 18; ++s) {
      const int tap = s >> 1, ks = s & 1;
      const int dh = tap / 3, dw = tap - dh * 3;
      bf16x8 wf[4], pf[4];
#pragma unroll
      for (int c = 0; c < 4; ++c)
        wf[c] = *reinterpret_cast<const bf16x8*>(&lds[WOFF + (s * 4 + c) * 1024 + l * 16]);
      const int Pr = wv * 16 + lo + dw;
      const int c8 = (ks << 2) | grp;
      const int pbyte = Pr * 128 + ((c8 ^ (Pr & 7)) << 4);
#pragma unroll
      for (int p = 0; p < 4; ++p) {
        const int rr = p + dh;             // compile-time 0..5
        const int rbr = (rr == 0) ? rb0 : (rr == 1) ? rb1 : (rr == 2) ? rb2
                      : (rr == 3) ? rb3 : (rr == 4) ? rb4 : rb5;
        pf[p] = *reinterpret_cast<const bf16x8*>(&lds[rbr + pbyte]);
      }
#pragma unroll
      for (int c = 0; c < 4; ++c)
#pragma unroll
        for (int p = 0; p < 4; ++p)
          acc[c][p] = __builtin_amdgcn_mfma_f32_16x16x32_bf16(wf[c], pf[p], acc[c][p], 0, 0, 0);
    }

    // ---- epilogue (R6 order: before the restage barriers) ----
#pragma unroll
    for (int c = 0; c < 4; ++c) {
      const int co0 = c * 16 + grp * 4;
      float s_[4], h_[4], a_[4];
#pragma unroll
      for (int j = 0; j < 4; ++j) {
        s_[j] = scale[co0 + j];
        h_[j] = shift[co0 + j];
        a_[j] = aP[co0 + j];
      }
      const int w = wv * 16 + lo;
#pragma unroll
      for (int p = 0; p < 4; ++p) {
        const int hh = r0 + p;
        f32x4 v = acc[c][p];
        if (STAGE == 1) {
          u16x4 u;
#pragma unroll
          for (int j = 0; j < 4; ++j) {
            float vv = v[j] * s_[j] + h_[j];
            vv = vv >= 0.f ? vv : vv * a_[j];
            u[j] = f2bf(vv);
          }
          *reinterpret_cast<u16x4*>(dstb + (ibase + hh * Wimg + w) * 64 + co0) = u;
        } else {
#pragma unroll
          for (int j = 0; j < 4; ++j) {
            size_t idx = ((size_t)(n * 64 + co0 + j) * Himg + hh) * Wimg + w;
            float vv = v[j] * s_[j] + h_[j] + resid[idx];
            vv = vv >= 0.f ? vv : vv * a_[j];
            dstf[idx] = vv;
          }
        }
      }
    }

    // ---- restage ring (R6 order) ----
    if (T < 6) {
      __syncthreads();   // all waves done reading slots about to be overwritten
      if (STAGE == 1) {
        emit_rowx(rb0, pA[0], pB[0], pv[0]);
        emit_rowx(rb1, pA[1], pB[1], pv[1]);
#pragma unroll
        for (int rr = 2; rr < 4; ++rr) {
          f32x4 tA[2], tB[2];
          bool v = load_rowx(r0 + 5 + rr, tA, tB);
          emit_rowx((rr == 2) ? rb2 : rb3, tA, tB, v);
        }
      } else {
#pragma unroll
        for (int it = 0; it < 8; ++it) {
          int j = it >> 1;                   // compile-time
          int rem = t + (it & 1) * 448;
          int w = rem >> 3, k = rem & 7;
          int P = w + 1;
          const int dst = (j == 0) ? rb0 : (j == 1) ? rb1 : (j == 2) ? rb2 : rb3;
          *reinterpret_cast<u32x4*>(&lds[dst + P * 128 + ((k ^ (P & 7)) << 4)]) = preg[it];
        }
      }
      __syncthreads();
    }

    // rotate ring by 4 rows: new(0..5) = old(4,5,0,1,2,3)
    int n0 = rb4, n1 = rb5, n2 = rb0, n3 = rb1, n4 = rb2, n5 = rb3;
    rb0 = n0; rb1 = n1; rb2 = n2; rb3 = n3; rb4 = n4; rb5 = n5;
  }
}

// ---------------------------------------------------------------------------
// scratch map:
//   d_ws [0 .. 102,760,448)     : y1 bf16 NHWC
//   d_ws [+0 .. +73,728)        : wt1 packed bf16
//   d_ws [+73,728 .. +147,456)  : wt2 packed bf16
//   d_ws [+147,456 .. +149,000) : prm f32 (384 floats)
//   d_out: final output only (x0 intermediate eliminated)
// ---------------------------------------------------------------------------
extern "C" void kernel_launch(void* const* d_in, const int* in_sizes, int n_in,
                              void* d_out, int out_size, void* d_ws, size_t ws_size,
                              hipStream_t stream)
{
  const float* x  = (const float*)d_in[0];
  const float* w1 = (const float*)d_in[1];
  const float* w2 = (const float*)d_in[2];
  const float* g0 = (const float*)d_in[3];
  const float* b0 = (const float*)d_in[4];
  const float* m0 = (const float*)d_in[5];
  const float* v0 = (const float*)d_in[6];
  const float* g1 = (const float*)d_in[7];
  const float* b1 = (const float*)d_in[8];
  const float* m1 = (const float*)d_in[9];
  const float* v1 = (const float*)d_in[10];
  const float* g2 = (const float*)d_in[11];
  const float* b2 = (const float*)d_in[12];
  const float* m2 = (const float*)d_in[13];
  const float* v2 = (const float*)d_in[14];
  const float* a1 = (const float*)d_in[15];
  const float* a2 = (const float*)d_in[16];

  unsigned char* wsb = (unsigned char*)d_ws;
  unsigned short* y1  = (unsigned short*)wsb;
  unsigned short* wt1 = (unsigned short*)(wsb + 102760448);
  unsigned short* wt2 = (unsigned short*)(wsb + 102760448 + 73728);
  float* prm          = (float*)(wsb + 102760448 + 2 * 73728);

  prep_misc<<<16, 256, 0, stream>>>(w1, w2, g0, b0, m0, v0, g1, b1, m1, v1,
                                    g2, b2, m2, v2, wt1, wt2, prm);
  conv3x3p<1><<<256, 448, 0, stream>>>(nullptr, x, wt1, prm, prm + 64, a1,
                                       prm + 256, prm + 320, y1, nullptr, nullptr);
  conv3x3p<2><<<256, 448, 0, stream>>>(y1, nullptr, wt2, prm + 128, prm + 192, a2,
                                       nullptr, nullptr, nullptr, (float*)d_out, x);
}

// Round 15
// 250.869 us; speedup vs baseline: 1.5112x; 1.0531x over previous
//
#include <hip/hip_runtime.h>

#define EPSV 1e-5f

typedef __bf16 bf16x8 __attribute__((ext_vector_type(8)));
typedef float f32x4 __attribute__((ext_vector_type(4)));
typedef unsigned int u32x4 __attribute__((ext_vector_type(4)));
typedef unsigned short u16x4 __attribute__((ext_vector_type(4)));

__device__ __forceinline__ unsigned short f2bf(float f) {
  return __builtin_bit_cast(unsigned short, static_cast<__bf16>(f));
}

constexpr int Himg = 112, Wimg = 112, HWp = Himg * Wimg;  // 12544

// ---------------------------------------------------------------------------
// prep_misc: pack weights into per-lane MFMA A-fragment order + BN scale/shift
//   for all three BNs. prm: [0)=s1 [64)=h1 [128)=s2 [192)=h2 [256)=s0 [320)=h0
// ---------------------------------------------------------------------------
__global__ __launch_bounds__(256) void prep_misc(
    const float* __restrict__ w1, const float* __restrict__ w2,
    const float* __restrict__ g0, const float* __restrict__ b0,
    const float* __restrict__ m0, const float* __restrict__ v0,
    const float* __restrict__ g1, const float* __restrict__ b1,
    const float* __restrict__ m1, const float* __restrict__ v1,
    const float* __restrict__ g2, const float* __restrict__ b2,
    const float* __restrict__ m2, const float* __restrict__ v2,
    unsigned short* __restrict__ wt1, unsigned short* __restrict__ wt2,
    float* __restrict__ prm)
{
  int id = blockIdx.x * 256 + threadIdx.x;
  for (int i = id; i < 9 * 2 * 4 * 512; i += gridDim.x * 256) {
    int j   = i & 7;
    int l   = (i >> 3) & 63;
    int c   = (i >> 9) & 3;
    int ks  = (i >> 11) & 1;
    int tap = i >> 12;
    int co  = c * 16 + (l & 15);
    int ci  = ks * 32 + (l >> 4) * 8 + j;
    int kh  = tap / 3, kw = tap - kh * 3;
    int src = ((co * 64 + ci) * 3 + kh) * 3 + kw;
    wt1[i] = f2bf(w1[src]);
    wt2[i] = f2bf(w2[src]);
  }
  if (id < 64) {
    float s1 = g1[id] * rsqrtf(v1[id] + EPSV);
    prm[id]      = s1;
    prm[64 + id] = b1[id] - m1[id] * s1;
    float s2 = g2[id] * rsqrtf(v2[id] + EPSV);
    prm[128 + id] = s2;
    prm[192 + id] = b2[id] - m2[id] * s2;
    float s0 = g0[id] * rsqrtf(v0[id] + EPSV);
    prm[256 + id] = s0;
    prm[320 + id] = b0[id] - m0[id] * s0;
  }
}

// ---------------------------------------------------------------------------
// conv1k: R14's STAGE-1 kernel, unchanged. Persistent 256 blocks, 448 thr,
//   4-row tiles, x (NCHW f32) staged with fused BN0 -> y1 bf16 NHWC.
// ---------------------------------------------------------------------------
__global__ __launch_bounds__(448, 2) void conv1k(
    const float* __restrict__ xsrc,
    const unsigned short* __restrict__ wP,
    const float* __restrict__ scale, const float* __restrict__ shift,
    const float* __restrict__ aP,
    const float* __restrict__ bn0sc, const float* __restrict__ bn0sh,
    unsigned short* __restrict__ dstb)
{
  constexpr int RS   = 114 * 128;   // 14592
  constexpr int WOFF = 6 * RS;      // 87552
  __shared__ __align__(16) unsigned char lds[WOFF + 73728];  // 161280

  const int t = threadIdx.x;
  const int b = blockIdx.x;
  const int n = b >> 2, q = b & 3;
  const int qbase = q * 28;
  const size_t ibase = (size_t)n * HWp;
  const float* xn = xsrc + (size_t)n * 64 * HWp;

  const int wv = t >> 6, l = t & 63;
  const int lo = l & 15, grp = l >> 4;

  const int cs = t / 28, wb = t - cs * 28;
  const int w0s = wb * 4;
  float scv[4], shv[4];
#pragma unroll
  for (int cc = 0; cc < 4; ++cc) {
    scv[cc] = bn0sc[cs * 4 + cc];
    shv[cc] = bn0sh[cs * 4 + cc];
  }

  auto load_rowx = [&](int hh, f32x4 (&A)[2], f32x4 (&B)[2]) -> bool {
    bool valid = (unsigned)hh < 112u;
#pragma unroll
    for (int u = 0; u < 2; ++u) {
      f32x4 z = {0.f, 0.f, 0.f, 0.f};
      A[u] = z; B[u] = z;
      if (valid) {
        const int ca = cs * 4 + u * 2;
        A[u] = *reinterpret_cast<const f32x4*>(xn + (size_t)ca * HWp + hh * Wimg + w0s);
        B[u] = *reinterpret_cast<const f32x4*>(xn + (size_t)(ca + 1) * HWp + hh * Wimg + w0s);
      }
    }
    return valid;
  };
  auto emit_rowx = [&](int rbX, const f32x4 (&A)[2], const f32x4 (&B)[2], bool valid) {
#pragma unroll
    for (int u = 0; u < 2; ++u) {
      const int ca = cs * 4 + u * 2;
      const int kk = ca >> 3;
      const int off = (ca & 7) * 2;
#pragma unroll
      for (int j = 0; j < 4; ++j) {
        float fa = valid ? A[u][j] * scv[u * 2] + shv[u * 2] : 0.f;
        float fb = valid ? B[u][j] * scv[u * 2 + 1] + shv[u * 2 + 1] : 0.f;
        unsigned int pk = (unsigned int)f2bf(fa) | ((unsigned int)f2bf(fb) << 16);
        int P = w0s + j + 1;
        *reinterpret_cast<unsigned int*>(
            &lds[rbX + P * 128 + ((kk ^ (P & 7)) << 4) + off]) = pk;
      }
    }
  };

#pragma unroll
  for (int it = 0; it < 11; ++it) {
    int idx = t + it * 448;
    if (it < 10 || idx < 4608) {
      u32x4 v = *reinterpret_cast<const u32x4*>(wP + idx * 8);
      *reinterpret_cast<u32x4*>(&lds[WOFF + idx * 16]) = v;
    }
  }
  if (t < 96) {
    int r = t >> 4, P = ((t >> 3) & 1) ? 113 : 0, k = t & 7;
    u32x4 z = {0u, 0u, 0u, 0u};
    *reinterpret_cast<u32x4*>(&lds[r * RS + P * 128 + ((k ^ (P & 7)) << 4)]) = z;
  }
#pragma unroll
  for (int r = 0; r < 6; ++r) {
    f32x4 A[2], B[2];
    bool v = load_rowx(qbase - 1 + r, A, B);
    emit_rowx(r * RS, A, B, v);
  }
  __syncthreads();

  int rb0 = 0 * RS, rb1 = 1 * RS, rb2 = 2 * RS, rb3 = 3 * RS, rb4 = 4 * RS, rb5 = 5 * RS;

  for (int T = 0; T < 7; ++T) {
    const int r0 = qbase + T * 4;

    f32x4 pA[2][2], pB[2][2];
    bool pv[2];
    if (T < 6) {
#pragma unroll
      for (int rr = 0; rr < 2; ++rr)
        pv[rr] = load_rowx(r0 + 5 + rr, pA[rr], pB[rr]);
    }

    f32x4 acc[4][4];
#pragma unroll
    for (int c = 0; c < 4; ++c)
#pragma unroll
      for (int p = 0; p < 4; ++p) {
        f32x4 z = {0.f, 0.f, 0.f, 0.f};
        acc[c][p] = z;
      }

#pragma unroll
    for (int s = 0; s < 18; ++s) {
      const int tap = s >> 1, ks = s & 1;
      const int dh = tap / 3, dw = tap - dh * 3;
      bf16x8 wf[4], pf[4];
#pragma unroll
      for (int c = 0; c < 4; ++c)
        wf[c] = *reinterpret_cast<const bf16x8*>(&lds[WOFF + (s * 4 + c) * 1024 + l * 16]);
      const int Pr = wv * 16 + lo + dw;
      const int c8 = (ks << 2) | grp;
      const int pbyte = Pr * 128 + ((c8 ^ (Pr & 7)) << 4);
#pragma unroll
      for (int p = 0; p < 4; ++p) {
        const int rr = p + dh;
        const int rbr = (rr == 0) ? rb0 : (rr == 1) ? rb1 : (rr == 2) ? rb2
                      : (rr == 3) ? rb3 : (rr == 4) ? rb4 : rb5;
        pf[p] = *reinterpret_cast<const bf16x8*>(&lds[rbr + pbyte]);
      }
#pragma unroll
      for (int c = 0; c < 4; ++c)
#pragma unroll
        for (int p = 0; p < 4; ++p)
          acc[c][p] = __builtin_amdgcn_mfma_f32_16x16x32_bf16(wf[c], pf[p], acc[c][p], 0, 0, 0);
    }

#pragma unroll
    for (int c = 0; c < 4; ++c) {
      const int co0 = c * 16 + grp * 4;
      float s_[4], h_[4], a_[4];
#pragma unroll
      for (int j = 0; j < 4; ++j) {
        s_[j] = scale[co0 + j];
        h_[j] = shift[co0 + j];
        a_[j] = aP[co0 + j];
      }
      const int w = wv * 16 + lo;
#pragma unroll
      for (int p = 0; p < 4; ++p) {
        const int hh = r0 + p;
        f32x4 v = acc[c][p];
        u16x4 u;
#pragma unroll
        for (int j = 0; j < 4; ++j) {
          float vv = v[j] * s_[j] + h_[j];
          vv = vv >= 0.f ? vv : vv * a_[j];
          u[j] = f2bf(vv);
        }
        *reinterpret_cast<u16x4*>(dstb + (ibase + hh * Wimg + w) * 64 + co0) = u;
      }
    }

    if (T < 6) {
      __syncthreads();
      emit_rowx(rb0, pA[0], pB[0], pv[0]);
      emit_rowx(rb1, pA[1], pB[1], pv[1]);
#pragma unroll
      for (int rr = 2; rr < 4; ++rr) {
        f32x4 tA[2], tB[2];
        bool v = load_rowx(r0 + 5 + rr, tA, tB);
        emit_rowx((rr == 2) ? rb2 : rb3, tA, tB, v);
      }
      __syncthreads();
    }

    int n0 = rb4, n1 = rb5, n2 = rb0, n3 = rb1, n4 = rb2, n5 = rb3;
    rb0 = n0; rb1 = n1; rb2 = n2; rb3 = n3; rb4 = n4; rb5 = n5;
  }
}

// ---------------------------------------------------------------------------
// conv2k: NEW 2-row-tile conv2. Persistent 256 blocks, 448 thr = 7 waves.
//   Block owns (n=b>>2, rows q*28..q*28+27): 14 tiles of 2 rows x 112 w x 64co.
//   LDS 132096 B: ring 4 x [114][128B] XOR-swz + full weights [18][4][1024B].
//   Register working set shrunk (acc 32, preg 16) so a HALF-resid prefetch
//   (cofrags 0-1, 16 f32) fits under the 128-VGPR cap that killed R12/R13's
//   64-reg version. rres issued before the K-loop (latency hides under it);
//   cofrags 2-3 load resid inline as before.
// ---------------------------------------------------------------------------
__global__ __launch_bounds__(448, 2) void conv2k(
    const unsigned short* __restrict__ src,   // y1 bf16 NHWC
    const unsigned short* __restrict__ wP,
    const float* __restrict__ scale, const float* __restrict__ shift,
    const float* __restrict__ aP,
    float* __restrict__ dstf,
    const float* __restrict__ resid)
{
  constexpr int RS   = 114 * 128;   // 14592
  constexpr int WOFF = 4 * RS;      // 58368
  __shared__ __align__(16) unsigned char lds[WOFF + 73728];  // 132096

  const int t = threadIdx.x;
  const int b = blockIdx.x;
  const int n = b >> 2, q = b & 3;
  const int qbase = q * 28;
  const size_t ibase = (size_t)n * HWp;

  const int wv = t >> 6, l = t & 63;
  const int lo = l & 15, grp = l >> 4;

  // weights full (once)
#pragma unroll
  for (int it = 0; it < 11; ++it) {
    int idx = t + it * 448;
    if (it < 10 || idx < 4608) {
      u32x4 v = *reinterpret_cast<const u32x4*>(wP + idx * 8);
      *reinterpret_cast<u32x4*>(&lds[WOFF + idx * 16]) = v;
    }
  }
  // halo zero: 4 slots x 2 cols x 8 chunks
  if (t < 64) {
    int r = t >> 4, P = ((t >> 3) & 1) ? 113 : 0, k = t & 7;
    u32x4 z = {0u, 0u, 0u, 0u};
    *reinterpret_cast<u32x4*>(&lds[r * RS + P * 128 + ((k ^ (P & 7)) << 4)]) = z;
  }
  // ring prologue: rows qbase-1 .. qbase+2 -> slots 0..3
#pragma unroll
  for (int it = 0; it < 8; ++it) {
    int r = it >> 1;
    int rem = t + (it & 1) * 448;
    int w = rem >> 3, k = rem & 7;
    int hh = qbase - 1 + r;
    u32x4 val = {0u, 0u, 0u, 0u};
    if ((unsigned)hh < 112u)
      val = *reinterpret_cast<const u32x4*>(src + (ibase + hh * Wimg + w) * 64 + k * 8);
    int P = w + 1;
    *reinterpret_cast<u32x4*>(&lds[r * RS + P * 128 + ((k ^ (P & 7)) << 4)]) = val;
  }
  __syncthreads();

  int rb0 = 0 * RS, rb1 = 1 * RS, rb2 = 2 * RS, rb3 = 3 * RS;

  for (int T = 0; T < 14; ++T) {
    const int r0 = qbase + T * 2;

    // half-resid prefetch: cofrags 0-1 (16 f32), hides under K-loop
    float rres[2][2][4];
#pragma unroll
    for (int c = 0; c < 2; ++c)
#pragma unroll
      for (int p = 0; p < 2; ++p)
#pragma unroll
        for (int j = 0; j < 4; ++j) {
          size_t idx = ((size_t)(n * 64 + c * 16 + grp * 4 + j) * Himg + (r0 + p)) * Wimg
                       + wv * 16 + lo;
          rres[c][p][j] = resid[idx];
        }

    // preg: next tile's input rows r0+3, r0+4
    u32x4 preg[4];
    if (T < 13) {
#pragma unroll
      for (int it = 0; it < 4; ++it) {
        int j = it >> 1;
        int rem = t + (it & 1) * 448;
        int w = rem >> 3, k = rem & 7;
        int hh = r0 + 3 + j;
        u32x4 val = {0u, 0u, 0u, 0u};
        if (hh < 112)
          val = *reinterpret_cast<const u32x4*>(src + (ibase + hh * Wimg + w) * 64 + k * 8);
        preg[it] = val;
      }
    }
    __builtin_amdgcn_sched_barrier(0);

    f32x4 acc[4][2];
#pragma unroll
    for (int c = 0; c < 4; ++c)
#pragma unroll
      for (int p = 0; p < 2; ++p) {
        f32x4 z = {0.f, 0.f, 0.f, 0.f};
        acc[c][p] = z;
      }

    // K-loop: 18 steps, pure LDS + MFMA
#pragma unroll
    for (int s = 0; s < 18; ++s) {
      const int tap = s >> 1, ks = s & 1;
      const int dh = tap / 3, dw = tap - dh * 3;
      bf16x8 wf[4], pf[2];
#pragma unroll
      for (int c = 0; c < 4; ++c)
        wf[c] = *reinterpret_cast<const bf16x8*>(&lds[WOFF + (s * 4 + c) * 1024 + l * 16]);
      const int Pr = wv * 16 + lo + dw;
      const int c8 = (ks << 2) | grp;
      const int pbyte = Pr * 128 + ((c8 ^ (Pr & 7)) << 4);
#pragma unroll
      for (int p = 0; p < 2; ++p) {
        const int rr = p + dh;             // 0..3
        const int rbr = (rr == 0) ? rb0 : (rr == 1) ? rb1 : (rr == 2) ? rb2 : rb3;
        pf[p] = *reinterpret_cast<const bf16x8*>(&lds[rbr + pbyte]);
      }
#pragma unroll
      for (int c = 0; c < 4; ++c)
#pragma unroll
        for (int p = 0; p < 2; ++p)
          acc[c][p] = __builtin_amdgcn_mfma_f32_16x16x32_bf16(wf[c], pf[p], acc[c][p], 0, 0, 0);
    }

    // epilogue: cofrags 0-1 use prefetched resid; 2-3 inline
#pragma unroll
    for (int c = 0; c < 4; ++c) {
      const int co0 = c * 16 + grp * 4;
      float s_[4], h_[4], a_[4];
#pragma unroll
      for (int j = 0; j < 4; ++j) {
        s_[j] = scale[co0 + j];
        h_[j] = shift[co0 + j];
        a_[j] = aP[co0 + j];
      }
      const int w = wv * 16 + lo;
#pragma unroll
      for (int p = 0; p < 2; ++p) {
        const int hh = r0 + p;
        f32x4 v = acc[c][p];
#pragma unroll
        for (int j = 0; j < 4; ++j) {
          size_t idx = ((size_t)(n * 64 + co0 + j) * Himg + hh) * Wimg + w;
          float res = (c < 2) ? rres[c & 1][p][j] : resid[idx];
          float vv = v[j] * s_[j] + h_[j] + res;
          vv = vv >= 0.f ? vv : vv * a_[j];
          dstf[idx] = vv;
        }
      }
    }

    // restage ring
    if (T < 13) {
      __syncthreads();
#pragma unroll
      for (int it = 0; it < 4; ++it) {
        int j = it >> 1;
        int rem = t + (it & 1) * 448;
        int w = rem >> 3, k = rem & 7;
        int P = w + 1;
        const int dst = (j == 0) ? rb0 : rb1;
        *reinterpret_cast<u32x4*>(&lds[dst + P * 128 + ((k ^ (P & 7)) << 4)]) = preg[it];
      }
      __syncthreads();
    }

    // rotate ring by 2 rows: (0,1,2,3) -> (2,3,0,1)
    int n0 = rb2, n1 = rb3, n2 = rb0, n3 = rb1;
    rb0 = n0; rb1 = n1; rb2 = n2; rb3 = n3;
  }
}

// ---------------------------------------------------------------------------
// scratch map:
//   d_ws [0 .. 102,760,448)     : y1 bf16 NHWC
//   d_ws [+0 .. +73,728)        : wt1 packed bf16
//   d_ws [+73,728 .. +147,456)  : wt2 packed bf16
//   d_ws [+147,456 .. +149,000) : prm f32 (384 floats)
// ---------------------------------------------------------------------------
extern "C" void kernel_launch(void* const* d_in, const int* in_sizes, int n_in,
                              void* d_out, int out_size, void* d_ws, size_t ws_size,
                              hipStream_t stream)
{
  const float* x  = (const float*)d_in[0];
  const float* w1 = (const float*)d_in[1];
  const float* w2 = (const float*)d_in[2];
  const float* g0 = (const float*)d_in[3];
  const float* b0 = (const float*)d_in[4];
  const float* m0 = (const float*)d_in[5];
  const float* v0 = (const float*)d_in[6];
  const float* g1 = (const float*)d_in[7];
  const float* b1 = (const float*)d_in[8];
  const float* m1 = (const float*)d_in[9];
  const float* v1 = (const float*)d_in[10];
  const float* g2 = (const float*)d_in[11];
  const float* b2 = (const float*)d_in[12];
  const float* m2 = (const float*)d_in[13];
  const float* v2 = (const float*)d_in[14];
  const float* a1 = (const float*)d_in[15];
  const float* a2 = (const float*)d_in[16];

  unsigned char* wsb = (unsigned char*)d_ws;
  unsigned short* y1  = (unsigned short*)wsb;
  unsigned short* wt1 = (unsigned short*)(wsb + 102760448);
  unsigned short* wt2 = (unsigned short*)(wsb + 102760448 + 73728);
  float* prm          = (float*)(wsb + 102760448 + 2 * 73728);

  prep_misc<<<16, 256, 0, stream>>>(w1, w2, g0, b0, m0, v0, g1, b1, m1, v1,
                                    g2, b2, m2, v2, wt1, wt2, prm);
  conv1k<<<256, 448, 0, stream>>>(x, wt1, prm, prm + 64, a1, prm + 256, prm + 320, y1);
  conv2k<<<256, 448, 0, stream>>>(y1, wt2, prm + 128, prm + 192, a2, (float*)d_out, x);
}